// Round 1
// baseline (475.815 us; speedup 1.0000x reference)
//
#include <hip/hip_runtime.h>

#define B_ 16
#define T_ 4096
#define D_ 128
#define L_ 128
#define NC_ 32            // T_/L_
#define CH_ (B_*NC_)      // 512 chunks

__device__ __forceinline__ float clampf(float x, float lo, float hi) {
    return fminf(fmaxf(x, lo), hi);
}
__device__ __forceinline__ float phi_f(float x) {   // elu(x)+1
    return x > 0.f ? x + 1.f : expf(x);
}
__device__ __forceinline__ float4 phi4(float4 a) {
    float4 r; r.x = phi_f(a.x); r.y = phi_f(a.y); r.z = phi_f(a.z); r.w = phi_f(a.w); return r;
}

// ---------------- K0: per-chunk inclusive cumulative log-decays ----------------
__global__ void k0_logs(const float* __restrict__ beta,
                        const float* __restrict__ bb1, const float* __restrict__ bb2,
                        float* __restrict__ lg1, float* __restrict__ lg2) {
    int blk = blockIdx.x;
    int b = blk / NC_, c = blk % NC_;
    int t = threadIdx.x;            // 0..127
    __shared__ float s1[L_], s2[L_];
    float b1b = clampf(1.f / (1.f + expf(-bb1[0])), 0.01f, 0.995f);
    float b2b = clampf(1.f / (1.f + expf(-bb2[0])), 0.01f, 0.995f);
    float be = clampf(beta[b * T_ + c * L_ + t], 0.01f, 0.995f);
    float x1 = logf(clampf(b1b * be, 0.01f, 0.995f));
    float x2 = logf(clampf(b2b * be, 0.01f, 0.995f));
    s1[t] = x1; s2[t] = x2;
    __syncthreads();
    for (int off = 1; off < L_; off <<= 1) {
        float a1 = (t >= off) ? s1[t - off] : 0.f;
        float a2 = (t >= off) ? s2[t - off] : 0.f;
        __syncthreads();
        s1[t] += a1; s2[t] += a2;
        __syncthreads();
    }
    lg1[b * T_ + c * L_ + t] = s1[t];
    lg2[b * T_ + c * L_ + t] = s2[t];
}

// ---------------- K1: per-chunk state contribution C = sum_s w_s k'_s v_s^T ----------------
__global__ __launch_bounds__(256) void k1_chunkC(
        const float* __restrict__ kk, const float* __restrict__ vv,
        const float* __restrict__ mask,
        const float* __restrict__ lg1, const float* __restrict__ lg2,
        float* __restrict__ Cws) {
    int ch = blockIdx.x, st = blockIdx.y;
    int b = ch / NC_, c = ch % NC_;
    const float* lg = st ? lg2 : lg1;
    int tbase = b * T_ + c * L_;
    __shared__ float wL[L_];
    __shared__ float Ksl[16 * 128];   // [s][d]  (w*phi(k)*m folded in)
    __shared__ float Vsl[16 * 128];   // [s][e]
    int tid = threadIdx.x;
    if (tid < L_) {
        float tot = lg[tbase + L_ - 1];
        wL[tid] = expf(tot - lg[tbase + tid]);
    }
    __syncthreads();
    float acc[8][8];
#pragma unroll
    for (int r = 0; r < 8; r++)
#pragma unroll
        for (int cc = 0; cc < 8; cc++) acc[r][cc] = 0.f;
    int ti = tid >> 4, tj = tid & 15;
    int d0 = ti * 8, e0 = tj * 8;
    for (int sb = 0; sb < L_; sb += 16) {
        for (int i = tid; i < 512; i += 256) {
            int s = i >> 5, d4 = i & 31;
            int gt = tbase + sb + s;
            float4 kq = *(const float4*)&kk[(size_t)gt * D_ + d4 * 4];
            float m = mask[gt] * wL[sb + s];
            float4 ks = phi4(kq);
            ks.x *= m; ks.y *= m; ks.z *= m; ks.w *= m;
            *(float4*)&Ksl[s * 128 + d4 * 4] = ks;
            *(float4*)&Vsl[s * 128 + d4 * 4] = *(const float4*)&vv[(size_t)gt * D_ + d4 * 4];
        }
        __syncthreads();
#pragma unroll
        for (int s = 0; s < 16; s++) {
            float4 ka = *(float4*)&Ksl[s * 128 + d0];
            float4 kb = *(float4*)&Ksl[s * 128 + d0 + 4];
            float4 va = *(float4*)&Vsl[s * 128 + e0];
            float4 vb = *(float4*)&Vsl[s * 128 + e0 + 4];
            float kr[8] = {ka.x, ka.y, ka.z, ka.w, kb.x, kb.y, kb.z, kb.w};
            float vc[8] = {va.x, va.y, va.z, va.w, vb.x, vb.y, vb.z, vb.w};
#pragma unroll
            for (int r = 0; r < 8; r++)
#pragma unroll
                for (int cc = 0; cc < 8; cc++) acc[r][cc] += kr[r] * vc[cc];
        }
        __syncthreads();
    }
    float* Cout = Cws + ((size_t)(st * B_ + b) * NC_ + c) * (D_ * D_);
#pragma unroll
    for (int r = 0; r < 8; r++) {
        *(float4*)&Cout[(size_t)(d0 + r) * D_ + e0]     = make_float4(acc[r][0], acc[r][1], acc[r][2], acc[r][3]);
        *(float4*)&Cout[(size_t)(d0 + r) * D_ + e0 + 4] = make_float4(acc[r][4], acc[r][5], acc[r][6], acc[r][7]);
    }
}

// ---------------- K1z: per-chunk z contribution ----------------
__global__ void k1z(const float* __restrict__ kk, const float* __restrict__ mask,
                    const float* __restrict__ lg1, const float* __restrict__ lg2,
                    float* __restrict__ zc) {
    int ch = blockIdx.x, st = blockIdx.y;
    int b = ch / NC_, c = ch % NC_;
    const float* lg = st ? lg2 : lg1;
    int tbase = b * T_ + c * L_;
    __shared__ float wL[L_];
    int d = threadIdx.x;   // 0..127
    {
        float tot = lg[tbase + L_ - 1];
        wL[d] = expf(tot - lg[tbase + d]);
    }
    __syncthreads();
    float acc = 0.f;
    for (int s = 0; s < L_; s++) {
        float x = kk[(size_t)(tbase + s) * D_ + d];
        acc += wL[s] * phi_f(x) * mask[tbase + s];
    }
    zc[((size_t)(st * B_ + b) * NC_ + c) * D_ + d] = acc;
}

// ---------------- K2: chunk-state scan over C (overwrite with chunk-START state) ----------------
__global__ void k2_scan(float* __restrict__ Cws,
                        const float* __restrict__ lg1, const float* __restrict__ lg2) {
    size_t g = (size_t)blockIdx.x * blockDim.x + threadIdx.x;   // 2*B*D*D total
    int st = (int)(g / ((size_t)B_ * D_ * D_));
    size_t rem = g % ((size_t)B_ * D_ * D_);
    int b = (int)(rem / (D_ * D_));
    int de = (int)(rem % (D_ * D_));
    const float* lg = st ? lg2 : lg1;
    size_t base = ((size_t)(st * B_ + b) * NC_) * (D_ * D_) + de;
    float run = 0.f;
    for (int c = 0; c < NC_; c++) {
        float a = expf(lg[b * T_ + c * L_ + L_ - 1]);
        float tmp = Cws[base + (size_t)c * (D_ * D_)];
        Cws[base + (size_t)c * (D_ * D_)] = run;
        run = a * run + tmp;
    }
}

__global__ void k2z_scan(float* __restrict__ zc,
                         const float* __restrict__ lg1, const float* __restrict__ lg2) {
    int g = blockIdx.x * blockDim.x + threadIdx.x;   // 2*B*D total
    int st = g / (B_ * D_);
    int rem = g % (B_ * D_);
    int b = rem / D_;
    int d = rem % D_;
    const float* lg = st ? lg2 : lg1;
    size_t base = ((size_t)(st * B_ + b) * NC_) * D_ + d;
    float run = 0.f;
    for (int c = 0; c < NC_; c++) {
        float a = expf(lg[b * T_ + c * L_ + L_ - 1]);
        float tmp = zc[base + (size_t)c * D_];
        zc[base + (size_t)c * D_] = run;
        run = a * run + tmp;
    }
}

// ---------------- K3: per-chunk output ----------------
__global__ __launch_bounds__(256) void k3_out(
        const float* __restrict__ qq, const float* __restrict__ kk, const float* __restrict__ vv,
        const float* __restrict__ mask,
        const float* __restrict__ lg1, const float* __restrict__ lg2,
        const float* __restrict__ Hws, const float* __restrict__ Zws,
        float* __restrict__ out) {
    int ch = blockIdx.x;
    int b = ch / NC_, c = ch % NC_;
    int tbase = b * T_ + c * L_;
    int tid = threadIdx.x;
    int ti = tid >> 4, tj = tid & 15;
    int t0 = ti * 8, e0 = tj * 8;

    __shared__ float Ss[L_ * L_];       // 64 KB: S then P
    __shared__ float Asl[L_ * 16];      // A slices (Q) [t][16]
    __shared__ float Bsl[16 * L_];      // B slices [k][n]
    __shared__ float B2sl[16 * L_];
    __shared__ float lg1L[L_], lg2L[L_], A1L[L_], A2L[L_], rowsum[L_], denL[L_], mskL[L_];
    __shared__ float Z1s[D_], Z2s[D_];

    if (tid < L_) {
        float l1 = lg1[tbase + tid], l2 = lg2[tbase + tid];
        lg1L[tid] = l1; lg2L[tid] = l2;
        A1L[tid] = expf(l1); A2L[tid] = expf(l2);
        rowsum[tid] = 0.f;
        mskL[tid] = mask[tbase + tid];
        Z1s[tid] = Zws[((size_t)(0 * B_ + b) * NC_ + c) * D_ + tid];
        Z2s[tid] = Zws[((size_t)(1 * B_ + b) * NC_ + c) * D_ + tid];
    }
    __syncthreads();

    // den inter-chunk part: den[t] = A1*q.Z1s + A2*q.Z2s
    if (tid < L_) {
        int t = tid;
        float a1 = 0.f, a2 = 0.f;
        for (int d4 = 0; d4 < D_ / 4; d4++) {
            float4 qv = *(const float4*)&qq[(size_t)(tbase + t) * D_ + d4 * 4];
            float p0 = phi_f(qv.x), p1 = phi_f(qv.y), p2 = phi_f(qv.z), p3 = phi_f(qv.w);
            a1 += p0 * Z1s[d4 * 4] + p1 * Z1s[d4 * 4 + 1] + p2 * Z1s[d4 * 4 + 2] + p3 * Z1s[d4 * 4 + 3];
            a2 += p0 * Z2s[d4 * 4] + p1 * Z2s[d4 * 4 + 1] + p2 * Z2s[d4 * 4 + 2] + p3 * Z2s[d4 * 4 + 3];
        }
        denL[t] = A1L[t] * a1 + A2L[t] * a2;
    }

    float acc[8][8];
#pragma unroll
    for (int r = 0; r < 8; r++)
#pragma unroll
        for (int cc = 0; cc < 8; cc++) acc[r][cc] = 0.f;

    // -------- S = Q K'^T  (A staged [t][16], B staged transposed [dd][s]) --------
    for (int db = 0; db < D_; db += 16) {
        for (int i = tid; i < 512; i += 256) {
            int row = i >> 2, d4 = i & 3;
            float4 qv = *(const float4*)&qq[(size_t)(tbase + row) * D_ + db + d4 * 4];
            *(float4*)&Asl[row * 16 + d4 * 4] = phi4(qv);
        }
        for (int i = tid; i < 512; i += 256) {
            int s = i >> 2, d4 = i & 3;
            float4 kv = *(const float4*)&kk[(size_t)(tbase + s) * D_ + db + d4 * 4];
            float m = mskL[s];
            Bsl[(d4 * 4 + 0) * L_ + s] = phi_f(kv.x) * m;
            Bsl[(d4 * 4 + 1) * L_ + s] = phi_f(kv.y) * m;
            Bsl[(d4 * 4 + 2) * L_ + s] = phi_f(kv.z) * m;
            Bsl[(d4 * 4 + 3) * L_ + s] = phi_f(kv.w) * m;
        }
        __syncthreads();
#pragma unroll
        for (int dd = 0; dd < 16; dd++) {
            float4 b0 = *(float4*)&Bsl[dd * L_ + tj * 8];
            float4 b1 = *(float4*)&Bsl[dd * L_ + tj * 8 + 4];
            float bb[8] = {b0.x, b0.y, b0.z, b0.w, b1.x, b1.y, b1.z, b1.w};
#pragma unroll
            for (int r = 0; r < 8; r++) {
                float av = Asl[(t0 + r) * 16 + dd];
#pragma unroll
                for (int cc = 0; cc < 8; cc++) acc[r][cc] += av * bb[cc];
            }
        }
        __syncthreads();
    }

    // -------- decay/mask -> P, rowsum, store to LDS --------
#pragma unroll
    for (int r = 0; r < 8; r++) {
        int t = t0 + r;
        float l1t = lg1L[t], l2t = lg2L[t];
        float rs = 0.f;
        float pv[8];
#pragma unroll
        for (int cc = 0; cc < 8; cc++) {
            int s = tj * 8 + cc;
            float p = 0.f;
            if (s <= t) p = acc[r][cc] * (expf(l1t - lg1L[s]) + expf(l2t - lg2L[s]));
            pv[cc] = p; rs += p;
        }
        *(float4*)&Ss[t * L_ + tj * 8]     = make_float4(pv[0], pv[1], pv[2], pv[3]);
        *(float4*)&Ss[t * L_ + tj * 8 + 4] = make_float4(pv[4], pv[5], pv[6], pv[7]);
        atomicAdd(&rowsum[t], rs);
    }
    __syncthreads();

    // -------- num = P @ V --------
#pragma unroll
    for (int r = 0; r < 8; r++)
#pragma unroll
        for (int cc = 0; cc < 8; cc++) acc[r][cc] = 0.f;
    for (int sb = 0; sb < L_; sb += 16) {
        for (int i = tid; i < 512; i += 256) {
            int s = i >> 5, e4 = i & 31;
            *(float4*)&Bsl[s * L_ + e4 * 4] = *(const float4*)&vv[(size_t)(tbase + sb + s) * D_ + e4 * 4];
        }
        __syncthreads();
#pragma unroll
        for (int j4 = 0; j4 < 16; j4 += 4) {
            float4 sreg[8];
#pragma unroll
            for (int r = 0; r < 8; r++) sreg[r] = *(float4*)&Ss[(t0 + r) * L_ + sb + j4];
#pragma unroll
            for (int j = 0; j < 4; j++) {
                float4 v0 = *(float4*)&Bsl[(j4 + j) * L_ + e0];
                float4 v1 = *(float4*)&Bsl[(j4 + j) * L_ + e0 + 4];
#pragma unroll
                for (int r = 0; r < 8; r++) {
                    float p = (j == 0) ? sreg[r].x : (j == 1) ? sreg[r].y : (j == 2) ? sreg[r].z : sreg[r].w;
                    acc[r][0] += p * v0.x; acc[r][1] += p * v0.y; acc[r][2] += p * v0.z; acc[r][3] += p * v0.w;
                    acc[r][4] += p * v1.x; acc[r][5] += p * v1.y; acc[r][6] += p * v1.z; acc[r][7] += p * v1.w;
                }
            }
        }
        __syncthreads();
    }

    // -------- num += diag(A1) Q H1s + diag(A2) Q H2s --------
    float a1r[8], a2r[8];
#pragma unroll
    for (int r = 0; r < 8; r++) { a1r[r] = A1L[t0 + r]; a2r[r] = A2L[t0 + r]; }
    const float* H1p = Hws + ((size_t)(0 * B_ + b) * NC_ + c) * (D_ * D_);
    const float* H2p = Hws + ((size_t)(1 * B_ + b) * NC_ + c) * (D_ * D_);
    for (int db = 0; db < D_; db += 16) {
        for (int i = tid; i < 512; i += 256) {
            int row = i >> 2, d4 = i & 3;
            float4 qv = *(const float4*)&qq[(size_t)(tbase + row) * D_ + db + d4 * 4];
            *(float4*)&Asl[row * 16 + d4 * 4] = phi4(qv);
        }
        for (int i = tid; i < 512; i += 256) {
            int dr = i >> 5, e4 = i & 31;
            *(float4*)&Bsl[dr * L_ + e4 * 4]  = *(const float4*)&H1p[(size_t)(db + dr) * D_ + e4 * 4];
            *(float4*)&B2sl[dr * L_ + e4 * 4] = *(const float4*)&H2p[(size_t)(db + dr) * D_ + e4 * 4];
        }
        __syncthreads();
#pragma unroll
        for (int dd = 0; dd < 16; dd++) {
            float4 h10 = *(float4*)&Bsl[dd * L_ + e0];
            float4 h11 = *(float4*)&Bsl[dd * L_ + e0 + 4];
            float4 h20 = *(float4*)&B2sl[dd * L_ + e0];
            float4 h21 = *(float4*)&B2sl[dd * L_ + e0 + 4];
#pragma unroll
            for (int r = 0; r < 8; r++) {
                float qv = Asl[(t0 + r) * 16 + dd];
                float q1 = qv * a1r[r], q2 = qv * a2r[r];
                acc[r][0] += q1 * h10.x + q2 * h20.x;
                acc[r][1] += q1 * h10.y + q2 * h20.y;
                acc[r][2] += q1 * h10.z + q2 * h20.z;
                acc[r][3] += q1 * h10.w + q2 * h20.w;
                acc[r][4] += q1 * h11.x + q2 * h21.x;
                acc[r][5] += q1 * h11.y + q2 * h21.y;
                acc[r][6] += q1 * h11.z + q2 * h21.z;
                acc[r][7] += q1 * h11.w + q2 * h21.w;
            }
        }
        __syncthreads();
    }

    // -------- finalize den, write out --------
    if (tid < L_) {
        float dv = denL[tid] + rowsum[tid];
        dv = fmaxf(dv, 1e-6f);
        denL[tid] = mskL[tid] / dv;
    }
    __syncthreads();
#pragma unroll
    for (int r = 0; r < 8; r++) {
        float sc = denL[t0 + r];
        float4 o0 = make_float4(acc[r][0] * sc, acc[r][1] * sc, acc[r][2] * sc, acc[r][3] * sc);
        float4 o1 = make_float4(acc[r][4] * sc, acc[r][5] * sc, acc[r][6] * sc, acc[r][7] * sc);
        *(float4*)&out[(size_t)(tbase + t0 + r) * D_ + e0]     = o0;
        *(float4*)&out[(size_t)(tbase + t0 + r) * D_ + e0 + 4] = o1;
    }
}

extern "C" void kernel_launch(void* const* d_in, const int* in_sizes, int n_in,
                              void* d_out, int out_size, void* d_ws, size_t ws_size,
                              hipStream_t stream) {
    const float* q    = (const float*)d_in[0];
    const float* k    = (const float*)d_in[1];
    const float* v    = (const float*)d_in[2];
    const float* beta = (const float*)d_in[3];
    const float* mask = (const float*)d_in[4];
    const float* bb1  = (const float*)d_in[5];
    const float* bb2  = (const float*)d_in[6];
    float* out = (float*)d_out;
    float* ws  = (float*)d_ws;

    size_t n_lg = (size_t)B_ * T_;                       // 65536
    size_t n_C  = (size_t)2 * B_ * NC_ * D_ * D_;        // 16777216
    size_t n_z  = (size_t)2 * B_ * NC_ * D_;             // 131072
    size_t need = (2 * n_lg + n_C + n_z) * sizeof(float);
    if (ws_size < need) return;   // fail visibly (output stays zero) rather than corrupt memory

    float* lg1 = ws;
    float* lg2 = lg1 + n_lg;
    float* Cws = lg2 + n_lg;
    float* zc  = Cws + n_C;

    k0_logs<<<CH_, L_, 0, stream>>>(beta, bb1, bb2, lg1, lg2);
    k1_chunkC<<<dim3(CH_, 2), 256, 0, stream>>>(k, v, mask, lg1, lg2, Cws);
    k1z<<<dim3(CH_, 2), L_, 0, stream>>>(k, mask, lg1, lg2, zc);
    k2_scan<<<(2 * B_ * D_ * D_) / 256, 256, 0, stream>>>(Cws, lg1, lg2);
    k2z_scan<<<(2 * B_ * D_) / 256, 256, 0, stream>>>(zc, lg1, lg2);
    k3_out<<<CH_, 256, 0, stream>>>(q, k, v, mask, lg1, lg2, Cws, zc, out);
}

// Round 2
// 117.440 us; speedup vs baseline: 4.0516x; 4.0516x over previous
//
#include <hip/hip_runtime.h>

#define B_ 16
#define T_ 4096
#define D_ 128
#define L_ 128
#define NC_ 32            // T_/L_
#define CH_ (B_*NC_)      // 512 chunks
#define LDK 136           // padded bf16 row stride (272B) -> <=2-way LDS bank conflicts

typedef __attribute__((ext_vector_type(8))) short bf16x8;
typedef __attribute__((ext_vector_type(4))) float f32x4;

__device__ __forceinline__ float clampf(float x, float lo, float hi) {
    return fminf(fmaxf(x, lo), hi);
}
__device__ __forceinline__ float phi_f(float x) {   // elu(x)+1
    return x > 0.f ? x + 1.f : expf(x);
}
__device__ __forceinline__ float4 phi4(float4 a) {
    float4 r; r.x = phi_f(a.x); r.y = phi_f(a.y); r.z = phi_f(a.z); r.w = phi_f(a.w); return r;
}
__device__ __forceinline__ unsigned short bf16r(float f) {  // RNE f32->bf16
    unsigned u = __builtin_bit_cast(unsigned, f);
    u += 0x7FFFu + ((u >> 16) & 1u);
    return (unsigned short)(u >> 16);
}
__device__ __forceinline__ float fbf(unsigned short h) {
    unsigned u = ((unsigned)h) << 16; return __builtin_bit_cast(float, u);
}
__device__ __forceinline__ f32x4 zero4() { f32x4 z; z[0]=0.f; z[1]=0.f; z[2]=0.f; z[3]=0.f; return z; }

// ---------------- K0: per-chunk inclusive cumulative log-decays ----------------
__global__ void k0_logs(const float* __restrict__ beta,
                        const float* __restrict__ bb1, const float* __restrict__ bb2,
                        float* __restrict__ lg1, float* __restrict__ lg2) {
    int blk = blockIdx.x;
    int b = blk / NC_, c = blk % NC_;
    int t = threadIdx.x;            // 0..127
    __shared__ float s1[L_], s2[L_];
    float b1b = clampf(1.f / (1.f + expf(-bb1[0])), 0.01f, 0.995f);
    float b2b = clampf(1.f / (1.f + expf(-bb2[0])), 0.01f, 0.995f);
    float be = clampf(beta[b * T_ + c * L_ + t], 0.01f, 0.995f);
    float x1 = logf(clampf(b1b * be, 0.01f, 0.995f));
    float x2 = logf(clampf(b2b * be, 0.01f, 0.995f));
    s1[t] = x1; s2[t] = x2;
    __syncthreads();
    for (int off = 1; off < L_; off <<= 1) {
        float a1 = (t >= off) ? s1[t - off] : 0.f;
        float a2 = (t >= off) ? s2[t - off] : 0.f;
        __syncthreads();
        s1[t] += a1; s2[t] += a2;
        __syncthreads();
    }
    lg1[b * T_ + c * L_ + t] = s1[t];
    lg2[b * T_ + c * L_ + t] = s2[t];
}

// ---------------- K1: per-chunk state contribution, MFMA, output TRANSPOSED bf16 ----------------
// Ct[e][d] = sum_s V[s][e] * (w_s * phiK[s][d] * m_s), both states in one block.
__global__ __launch_bounds__(256) void k1_mfma(
        const float* __restrict__ kk, const float* __restrict__ vv,
        const float* __restrict__ mask,
        const float* __restrict__ lg1, const float* __restrict__ lg2,
        unsigned short* __restrict__ Cws) {
    int ch = blockIdx.x;
    int b = ch / NC_, c = ch % NC_;
    int tbase = b * T_ + c * L_;
    int tid = threadIdx.x, lane = tid & 63, w = tid >> 6;

    __shared__ unsigned short sV[128 * LDK];   // Vt[e][s]
    __shared__ unsigned short sK[128 * LDK];   // (w*phiK*m)^T [d][s]
    __shared__ float wL[2][L_];

    if (tid < 128) {
        float tot1 = lg1[tbase + L_ - 1], tot2 = lg2[tbase + L_ - 1];
        wL[0][tid] = expf(tot1 - lg1[tbase + tid]);
        wL[1][tid] = expf(tot2 - lg2[tbase + tid]);
    }
    // stage Vt (transpose in-block): lane-consecutive s -> 2-way LDS write aliasing only
#pragma unroll
    for (int p = 0; p < 16; ++p) {
        int i = tid + p * 256;
        int s = i & 127, e4 = i >> 7;
        float4 vq = *(const float4*)&vv[(size_t)(tbase + s) * D_ + e4 * 4];
        sV[(e4 * 4 + 0) * LDK + s] = bf16r(vq.x);
        sV[(e4 * 4 + 1) * LDK + s] = bf16r(vq.y);
        sV[(e4 * 4 + 2) * LDK + s] = bf16r(vq.z);
        sV[(e4 * 4 + 3) * LDK + s] = bf16r(vq.w);
    }
    __syncthreads();

    for (int st = 0; st < 2; ++st) {
        // stage w*phiK*m transposed
#pragma unroll
        for (int p = 0; p < 16; ++p) {
            int i = tid + p * 256;
            int s = i & 127, d4 = i >> 7;
            float4 kq = *(const float4*)&kk[(size_t)(tbase + s) * D_ + d4 * 4];
            float m = mask[tbase + s] * wL[st][s];
            float4 pk = phi4(kq);
            sK[(d4 * 4 + 0) * LDK + s] = bf16r(pk.x * m);
            sK[(d4 * 4 + 1) * LDK + s] = bf16r(pk.y * m);
            sK[(d4 * 4 + 2) * LDK + s] = bf16r(pk.z * m);
            sK[(d4 * 4 + 3) * LDK + s] = bf16r(pk.w * m);
        }
        __syncthreads();

        f32x4 acc[2][8];
#pragma unroll
        for (int m = 0; m < 2; ++m)
#pragma unroll
            for (int n = 0; n < 8; ++n) acc[m][n] = zero4();
#pragma unroll
        for (int ks = 0; ks < 4; ++ks) {
            int koff = ks * 32 + (lane >> 4) * 8;
            bf16x8 a0 = *(const bf16x8*)&sV[(w * 32 + (lane & 15)) * LDK + koff];
            bf16x8 a1 = *(const bf16x8*)&sV[(w * 32 + 16 + (lane & 15)) * LDK + koff];
#pragma unroll
            for (int n = 0; n < 8; ++n) {
                bf16x8 bb = *(const bf16x8*)&sK[(n * 16 + (lane & 15)) * LDK + koff];
                acc[0][n] = __builtin_amdgcn_mfma_f32_16x16x32_bf16(a0, bb, acc[0][n], 0, 0, 0);
                acc[1][n] = __builtin_amdgcn_mfma_f32_16x16x32_bf16(a1, bb, acc[1][n], 0, 0, 0);
            }
        }
        unsigned short* Cp = Cws + ((size_t)(st * B_ + b) * NC_ + c) * (D_ * D_);
#pragma unroll
        for (int m = 0; m < 2; ++m)
#pragma unroll
            for (int n = 0; n < 8; ++n)
#pragma unroll
                for (int r = 0; r < 4; ++r) {
                    int e = w * 32 + m * 16 + (lane >> 4) * 4 + r;
                    int d = n * 16 + (lane & 15);
                    Cp[e * D_ + d] = bf16r(acc[m][n][r]);
                }
        __syncthreads();
    }
}

// ---------------- K1z: per-chunk z contribution (fp32, small) ----------------
__global__ void k1z(const float* __restrict__ kk, const float* __restrict__ mask,
                    const float* __restrict__ lg1, const float* __restrict__ lg2,
                    float* __restrict__ zc) {
    int ch = blockIdx.x, st = blockIdx.y;
    int b = ch / NC_, c = ch % NC_;
    const float* lg = st ? lg2 : lg1;
    int tbase = b * T_ + c * L_;
    __shared__ float wL[L_];
    int d = threadIdx.x;
    {
        float tot = lg[tbase + L_ - 1];
        wL[d] = expf(tot - lg[tbase + d]);
    }
    __syncthreads();
    float acc = 0.f;
    for (int s = 0; s < L_; s++) {
        float x = kk[(size_t)(tbase + s) * D_ + d];
        acc += wL[s] * phi_f(x) * mask[tbase + s];
    }
    zc[((size_t)(st * B_ + b) * NC_ + c) * D_ + d] = acc;
}

// ---------------- K2: chunk-state scan over Ct (bf16 storage, fp32 accum) ----------------
__global__ void k2_scan(unsigned short* __restrict__ Cws,
                        const float* __restrict__ lg1, const float* __restrict__ lg2) {
    size_t g = (size_t)blockIdx.x * blockDim.x + threadIdx.x;   // 2*B*D*D = 524288
    int st = (int)(g >> 18);
    int b = (int)((g >> 14) & 15);
    int de = (int)(g & 16383);
    const float* lg = st ? lg2 : lg1;
    size_t base = ((size_t)(st * B_ + b) * NC_) * (D_ * D_) + de;
    float run = 0.f;
    for (int c = 0; c < NC_; c++) {
        float a = expf(lg[b * T_ + c * L_ + L_ - 1]);
        float tmp = fbf(Cws[base + (size_t)c * (D_ * D_)]);
        Cws[base + (size_t)c * (D_ * D_)] = bf16r(run);
        run = a * run + tmp;
    }
}

__global__ void k2z_scan(float* __restrict__ zc,
                         const float* __restrict__ lg1, const float* __restrict__ lg2) {
    int g = blockIdx.x * blockDim.x + threadIdx.x;   // 2*B*D
    int st = g / (B_ * D_);
    int rem = g % (B_ * D_);
    int b = rem / D_;
    int d = rem % D_;
    const float* lg = st ? lg2 : lg1;
    size_t base = ((size_t)(st * B_ + b) * NC_) * D_ + d;
    float run = 0.f;
    for (int c = 0; c < NC_; c++) {
        float a = expf(lg[b * T_ + c * L_ + L_ - 1]);
        float tmp = zc[base + (size_t)c * D_];
        zc[base + (size_t)c * D_] = run;
        run = a * run + tmp;
    }
}

// ---------------- K3: per-half-chunk output, all GEMMs on MFMA ----------------
// block = (chunk, half): rows t in [half*64, half*64+64) of the chunk, 4 waves x 16 rows.
__global__ __launch_bounds__(256) void k3_mfma(
        const float* __restrict__ qq, const float* __restrict__ kk, const float* __restrict__ vv,
        const float* __restrict__ mask,
        const float* __restrict__ lg1, const float* __restrict__ lg2,
        const unsigned short* __restrict__ Cws, const float* __restrict__ zc,
        float* __restrict__ out) {
    int ch = blockIdx.x, hh = blockIdx.y;
    int b = ch / NC_, c = ch % NC_;
    int tbase = b * T_ + c * L_;
    int rbase = hh * 64;
    int tid = threadIdx.x, lane = tid & 63, w = tid >> 6;

    __shared__ unsigned short bufA[64 * LDK];    // phiQ, then P
    __shared__ unsigned short bufB[128 * LDK];   // H1t -> H2t -> phiK -> Vt
    __shared__ float sLg1[L_], sLg2[L_], sMsk[L_], sZ1[D_], sZ2[D_];
    __shared__ float sRow[64], sDen[64];

    if (tid < 128) {
        sLg1[tid] = lg1[tbase + tid];
        sLg2[tid] = lg2[tbase + tid];
        sMsk[tid] = mask[tbase + tid];
        sZ1[tid] = zc[((size_t)(0 * B_ + b) * NC_ + c) * D_ + tid];
        sZ2[tid] = zc[((size_t)(1 * B_ + b) * NC_ + c) * D_ + tid];
    }
    if (tid < 64) sRow[tid] = 0.f;

    // stage phiQ (64 rows) bf16 into bufA
#pragma unroll
    for (int p = 0; p < 8; ++p) {
        int i = tid + p * 256;          // 2048 quads
        int row = i >> 5, q4 = i & 31;
        float4 qv = *(const float4*)&qq[(size_t)(tbase + rbase + row) * D_ + q4 * 4];
        float4 pq = phi4(qv);
        bufA[row * LDK + q4 * 4 + 0] = bf16r(pq.x);
        bufA[row * LDK + q4 * 4 + 1] = bf16r(pq.y);
        bufA[row * LDK + q4 * 4 + 2] = bf16r(pq.z);
        bufA[row * LDK + q4 * 4 + 3] = bf16r(pq.w);
    }
    __syncthreads();   // S0: sLg/sZ/phiQ visible

    // den inter-chunk part (from the same bf16 phiQ -> correlated rounding)
    if (tid < 64) {
        int t = rbase + tid;
        float a1 = expf(sLg1[t]), a2 = expf(sLg2[t]);
        float d1 = 0.f, d2 = 0.f;
        for (int d = 0; d < D_; ++d) {
            float fq = fbf(bufA[tid * LDK + d]);
            d1 += fq * sZ1[d];
            d2 += fq * sZ2[d];
        }
        sDen[tid] = a1 * d1 + a2 * d2;
    }

    // per-lane row scales for QH phase
    float a1v[4], a2v[4];
#pragma unroll
    for (int r = 0; r < 4; ++r) {
        int t = rbase + w * 16 + (lane >> 4) * 4 + r;
        a1v[r] = expf(sLg1[t]);
        a2v[r] = expf(sLg2[t]);
    }

    f32x4 acc_o[8];
#pragma unroll
    for (int n = 0; n < 8; ++n) acc_o[n] = zero4();

    // -------- QH: acc_o += diag(A_st) * phiQ @ H_st --------
    for (int st = 0; st < 2; ++st) {
        const unsigned short* Hp = Cws + ((size_t)(st * B_ + b) * NC_ + c) * (D_ * D_);
#pragma unroll
        for (int p = 0; p < 8; ++p) {
            int i = tid + p * 256;       // 2048 groups of 8
            int e = i >> 4, g = i & 15;
            *(uint4*)&bufB[e * LDK + g * 8] = *(const uint4*)&Hp[e * D_ + g * 8];
        }
        __syncthreads();   // Ht staged (and for st=0: after S0 so bufB free)
        f32x4 at[8];
#pragma unroll
        for (int n = 0; n < 8; ++n) at[n] = zero4();
#pragma unroll
        for (int ks = 0; ks < 4; ++ks) {
            int koff = ks * 32 + (lane >> 4) * 8;
            bf16x8 a = *(const bf16x8*)&bufA[(w * 16 + (lane & 15)) * LDK + koff];
#pragma unroll
            for (int n = 0; n < 8; ++n) {
                bf16x8 bb = *(const bf16x8*)&bufB[(n * 16 + (lane & 15)) * LDK + koff];
                at[n] = __builtin_amdgcn_mfma_f32_16x16x32_bf16(a, bb, at[n], 0, 0, 0);
            }
        }
#pragma unroll
        for (int n = 0; n < 8; ++n)
#pragma unroll
            for (int r = 0; r < 4; ++r)
                acc_o[n][r] += (st ? a2v[r] : a1v[r]) * at[n][r];
        __syncthreads();   // bufB reads done before restage
    }

    // -------- S = phiQ @ (phiK*m)^T --------
#pragma unroll
    for (int p = 0; p < 16; ++p) {
        int i = tid + p * 256;           // 4096 quads
        int s = i >> 5, d4 = i & 31;
        float4 kv = *(const float4*)&kk[(size_t)(tbase + s) * D_ + d4 * 4];
        float m = sMsk[s];
        float4 pk = phi4(kv);
        bufB[s * LDK + d4 * 4 + 0] = bf16r(pk.x * m);
        bufB[s * LDK + d4 * 4 + 1] = bf16r(pk.y * m);
        bufB[s * LDK + d4 * 4 + 2] = bf16r(pk.z * m);
        bufB[s * LDK + d4 * 4 + 3] = bf16r(pk.w * m);
    }
    __syncthreads();
    f32x4 acc_s[8];
#pragma unroll
    for (int n = 0; n < 8; ++n) acc_s[n] = zero4();
#pragma unroll
    for (int ks = 0; ks < 4; ++ks) {
        int koff = ks * 32 + (lane >> 4) * 8;
        bf16x8 a = *(const bf16x8*)&bufA[(w * 16 + (lane & 15)) * LDK + koff];
#pragma unroll
        for (int n = 0; n < 8; ++n) {
            bf16x8 bb = *(const bf16x8*)&bufB[(n * 16 + (lane & 15)) * LDK + koff];
            acc_s[n] = __builtin_amdgcn_mfma_f32_16x16x32_bf16(a, bb, acc_s[n], 0, 0, 0);
        }
    }
    __syncthreads();   // S6: phiQ reads + phiK reads done; bufA/bufB free

    // -------- decay/mask -> P (bf16 into bufA), rowsum --------
    float rs[4] = {0.f, 0.f, 0.f, 0.f};
#pragma unroll
    for (int n = 0; n < 8; ++n) {
#pragma unroll
        for (int r = 0; r < 4; ++r) {
            int tl = w * 16 + (lane >> 4) * 4 + r;
            int trow = rbase + tl;
            int s = n * 16 + (lane & 15);
            float pval = 0.f;
            if (s <= trow)
                pval = acc_s[n][r] * (expf(sLg1[trow] - sLg1[s]) + expf(sLg2[trow] - sLg2[s]));
            rs[r] += pval;
            bufA[tl * LDK + s] = bf16r(pval);
        }
    }
#pragma unroll
    for (int r = 0; r < 4; ++r)
        atomicAdd(&sRow[w * 16 + (lane >> 4) * 4 + r], rs[r]);
    __syncthreads();   // S7: P visible, atomics done

    // den finalize
    if (tid < 64) {
        float dv = sDen[tid] + sRow[tid];
        sDen[tid] = sMsk[rbase + tid] / fmaxf(dv, 1e-6f);
    }
    // stage Vt (transpose in-block)
#pragma unroll
    for (int p = 0; p < 16; ++p) {
        int i = tid + p * 256;
        int s = i & 127, e4 = i >> 7;
        float4 vq = *(const float4*)&vv[(size_t)(tbase + s) * D_ + e4 * 4];
        bufB[(e4 * 4 + 0) * LDK + s] = bf16r(vq.x);
        bufB[(e4 * 4 + 1) * LDK + s] = bf16r(vq.y);
        bufB[(e4 * 4 + 2) * LDK + s] = bf16r(vq.z);
        bufB[(e4 * 4 + 3) * LDK + s] = bf16r(vq.w);
    }
    __syncthreads();   // S8

    // -------- acc_o += P @ V --------
#pragma unroll
    for (int ks = 0; ks < 4; ++ks) {
        int koff = ks * 32 + (lane >> 4) * 8;
        bf16x8 a = *(const bf16x8*)&bufA[(w * 16 + (lane & 15)) * LDK + koff];
#pragma unroll
        for (int n = 0; n < 8; ++n) {
            bf16x8 bb = *(const bf16x8*)&bufB[(n * 16 + (lane & 15)) * LDK + koff];
            acc_o[n] = __builtin_amdgcn_mfma_f32_16x16x32_bf16(a, bb, acc_o[n], 0, 0, 0);
        }
    }

    // -------- write out --------
#pragma unroll
    for (int n = 0; n < 8; ++n)
#pragma unroll
        for (int r = 0; r < 4; ++r) {
            int tl = w * 16 + (lane >> 4) * 4 + r;
            int e = n * 16 + (lane & 15);
            out[(size_t)(tbase + rbase + tl) * D_ + e] = acc_o[n][r] * sDen[tl];
        }
}

extern "C" void kernel_launch(void* const* d_in, const int* in_sizes, int n_in,
                              void* d_out, int out_size, void* d_ws, size_t ws_size,
                              hipStream_t stream) {
    const float* q    = (const float*)d_in[0];
    const float* k    = (const float*)d_in[1];
    const float* v    = (const float*)d_in[2];
    const float* beta = (const float*)d_in[3];
    const float* mask = (const float*)d_in[4];
    const float* bb1  = (const float*)d_in[5];
    const float* bb2  = (const float*)d_in[6];
    float* out = (float*)d_out;

    size_t n_lg = (size_t)B_ * T_;                       // 65536
    size_t n_z  = (size_t)2 * B_ * NC_ * D_;             // 131072
    size_t n_C  = (size_t)2 * B_ * NC_ * D_ * D_;        // 16777216 bf16 elems
    size_t need = (2 * n_lg + n_z) * sizeof(float) + n_C * sizeof(unsigned short);
    if (ws_size < need) return;

    float* lg1 = (float*)d_ws;
    float* lg2 = lg1 + n_lg;
    float* zc  = lg2 + n_lg;
    unsigned short* Cws = (unsigned short*)(zc + n_z);

    k0_logs<<<CH_, L_, 0, stream>>>(beta, bb1, bb2, lg1, lg2);
    k1_mfma<<<CH_, 256, 0, stream>>>(k, v, mask, lg1, lg2, Cws);
    k1z<<<dim3(CH_, 2), L_, 0, stream>>>(k, mask, lg1, lg2, zc);
    k2_scan<<<(2 * B_ * D_ * D_) / 256, 256, 0, stream>>>(Cws, lg1, lg2);
    k2z_scan<<<(2 * B_ * D_) / 256, 256, 0, stream>>>(zc, lg1, lg2);
    k3_mfma<<<dim3(CH_, 2), 256, 0, stream>>>(q, k, v, mask, lg1, lg2, Cws, zc, out);
}